// Round 16
// baseline (151.714 us; speedup 1.0000x reference)
//
#include <hip/hip_runtime.h>
#include <hip/hip_bf16.h>

#define F 1024
#define B_ROWS 16384

typedef short v8s __attribute__((ext_vector_type(8)));
typedef float v4f __attribute__((ext_vector_type(4)));
typedef unsigned short v8u __attribute__((ext_vector_type(8)));
typedef unsigned short ushort_t;

__device__ __forceinline__ unsigned short f2bf(float f) {
    unsigned int u = __builtin_bit_cast(unsigned int, f);
    u = (u + 0x7FFFu + ((u >> 16) & 1u)) >> 16;  // RNE
    return (unsigned short)u;
}

// async global->LDS, 16B per lane. LDS dest = wave-uniform base + lane*16.
__device__ __forceinline__ void gload_lds16(const ushort_t* g, ushort_t* l) {
    __builtin_amdgcn_global_load_lds(
        (const __attribute__((address_space(1))) unsigned int*)g,
        (__attribute__((address_space(3))) unsigned int*)l,
        16, 0, 0);
}

// Chunk (rb, cb) = 16-row x 32-col bf16 block stored [lane][8 bf16] in MFMA
// operand order: lane l -> row rb*16 + (l&15), cols cb*32 + (l>>4)*8..+8.
// One chunk = 1 KB. B = strictly upper-triangular W ((n,k) = w_{kn}, k<n).
//
// POISON LOG (keep forever):
//  - fused-sigmoid epilogue in gemm: CONVICTED (MfmaUtil 20->4.4%). Separate.
//  - X-pack fused as per-wave fp32 loads+cvts on MFMA path (r17): FAILED.
//  - K-split with extra blocks (r18): REGRESSION (prologue/refetch cost).
//  - fp32-A staged via global_load_lds + post-LDS cvt_pk (r20/r21): FAILED
//    (cvts+extra ds_reads on critical path; 4KB/lane-stride A-gather).
//  - ring-3/counted-vmcnt/no-drain barriers on the 128x128 16-MFMA/barrier
//    structure: 3x NEUTRAL (r16, r23/r24). nt-remap balance: NEUTRAL (r25).
//    The 128x128/BK=32 structure is plateaued at ~20% MfmaUtil -- its 16
//    MFMA/barrier (~80cyc cover) cannot hide ~500cyc staging latency.
//
// r26 (this): SCALE THE TILE so the simple 2-barrier schedule amortizes.
// BM=BN=256, BK=64, 512 threads = 8 waves (2M x 4N, wave tile 128x64).
// Per step: 64 chunks staged (32 A + 32 B = 8 gloads/wave), 24 ds_read_b128
// + 64 MFMA per wave = 512 MFMA/block per barrier (~2480 CU-cyc of cover vs
// ~500cyc staging latency -> drain nearly free). Same chunk machinery
// (zero bank conflicts by construction). LDS 2x64KB = 128KB dynamic
// (hipFuncSetAttribute), 1 block/CU, launch_bounds(512,2) -> 256 regs/wave
// (acc = 128 AGPR + ~90 VGPR fits). Triangular at BN=256: NT in 0..3,
// extent 4(NT+1) BK-steps (62.5% of full MACs). Per-M-tile jobs, balanced
// for 2-blocks-serial-per-CU: sizes 6,6,6,6 (blocks 0..255) then 4,4,4,4
// (blocks 256..511) -> every CU executes 6+4 = 10 steps.

// prep: [0,64) zero rowacc; [64,576) pack triangular B; [576,8768) pack X.
__global__ __launch_bounds__(256) void prep_kernel(
        const float* __restrict__ w, const float* __restrict__ x,
        ushort_t* __restrict__ Bp, ushort_t* __restrict__ Xp,
        float* __restrict__ acc) {
    const int bid  = blockIdx.x;
    const int tid  = threadIdx.x;
    const int lane = tid & 63;
    const int wave = tid >> 6;
    const int l16  = lane & 15;
    const int quad = lane >> 4;

    if (bid < 64) {
        acc[bid * 256 + tid] = 0.0f;
    } else if (bid < 576) {
        const int c  = (bid - 64) * 4 + wave;    // 0..2047
        const int n  = (c >> 5) * 16 + l16;      // output-col axis
        const int k0 = (c & 31) * 32 + quad * 8; // contraction axis
        v8u o;
#pragma unroll
        for (int e = 0; e < 8; ++e) {
            const int k = k0 + e;
            float v = 0.0f;
            if (k < n) {  // strictly upper: pair (k,n), k<n
                const int idx = k * (F - 1) - (k * (k - 1)) / 2 + (n - k - 1);
                v = w[idx];  // scattered read; w = 2MB, L2-resident
            }
            o[e] = f2bf(v);
        }
        *(v8u*)(Bp + (size_t)c * 512 + lane * 8) = o;
    } else {
        const int c  = (bid - 576) * 4 + wave;  // 0..32767
        const int r  = (c >> 5) * 16 + l16;     // X row
        const int k0 = (c & 31) * 32 + quad * 8;
        const float* src = x + (size_t)r * F + k0;
        float4 v0 = *(const float4*)(src);
        float4 v1 = *(const float4*)(src + 4);
        v8u o;
        o[0] = f2bf(v0.x); o[1] = f2bf(v0.y); o[2] = f2bf(v0.z); o[3] = f2bf(v0.w);
        o[4] = f2bf(v1.x); o[5] = f2bf(v1.y); o[6] = f2bf(v1.z); o[7] = f2bf(v1.w);
        *(v8u*)(Xp + (size_t)c * 512 + lane * 8) = o;
    }
}

// Job tables: block b in [0,512). h = b>>8 selects size class; j = b&3 the
// job; mt = (b>>2)&63 the M-tile. Coverage per (mt): NT0 [0,4); NT1 [0,8);
// NT2 [0,12); NT3 [0,16) -- exactly the triangular extents, once each.
__device__ __constant__ int JOB_NT[2][4] = {{2, 2, 3, 3}, {0, 1, 1, 3}};
__device__ __constant__ int JOB_C0[2][4] = {{0, 6, 0, 6}, {0, 0, 4, 12}};
__device__ __constant__ int JOB_NC[2][4] = {{6, 6, 6, 6}, {4, 4, 4, 4}};

// 256x256 GEMM, triangular-K, BK=64, 8 waves (r26).
// LDS (dynamic, 128KB): [buf(2)][slot(64)][1KB]; slots 0-31 = A chunks
// (rg-major, cb-minor), 32-63 = B chunks (ng-major, cb-minor).
__global__ __launch_bounds__(512, 2) void gemm_kernel(
        const ushort_t* __restrict__ Xp,   // packed X chunks
        const ushort_t* __restrict__ Bp,   // packed triangular-W chunks
        const float*   __restrict__ Xf,    // fp32 X (epilogue)
        float*         __restrict__ rowacc) {
    extern __shared__ ushort_t Ls[];

    const int b  = blockIdx.x;           // 0..511
    const int h  = b >> 8;               // size class: 0 -> 6 steps, 1 -> 4
    const int j  = b & 3;
    const int mt = (b >> 2) & 63;
    const int NT = JOB_NT[h][j];
    const int c0 = JOB_C0[h][j];
    const int nc = JOB_NC[h][j];
    const int blockM = mt * 256;
    const int blockN = NT * 256;
    const int tEnd   = c0 + nc;          // BK=64 steps: K < 256*(NT+1)

    const int tid   = threadIdx.x;
    const int lane  = tid & 63;
    const int wave  = tid >> 6;          // 0..7
    const int waveM = wave >> 2;         // 0..1
    const int waveN = wave & 3;          // 0..3
    const int quad  = lane >> 4;
    const int l16   = lane & 15;

    // Staging: 64 chunks/step, 8 per wave. qq<32: A chunk (rgl=qq>>1,
    // cbo=qq&1); qq>=32: B chunk likewise. LDS slot = qq.
    const int q0 = wave * 8;

#define STAGE(t, buf)                                                          \
    {                                                                          \
        _Pragma("unroll")                                                      \
        for (int q = 0; q < 8; ++q) {                                          \
            const int qq = q0 + q;                                             \
            const ushort_t* src;                                               \
            if (qq < 32) {                                                     \
                src = Xp + ((size_t)(mt * 16 + (qq >> 1)) * 32                 \
                            + 2 * (t) + (qq & 1)) * 512 + lane * 8;            \
            } else {                                                           \
                src = Bp + ((size_t)(NT * 16 + ((qq - 32) >> 1)) * 32          \
                            + 2 * (t) + (qq & 1)) * 512 + lane * 8;            \
            }                                                                  \
            gload_lds16(src, Ls + ((buf) * 64 + qq) * 512);                    \
        }                                                                      \
    }

    v4f acc[8][4];
#pragma unroll
    for (int i = 0; i < 8; i++)
#pragma unroll
        for (int jj = 0; jj < 4; jj++) acc[i][jj] = (v4f)(0.0f);

    v8s afr[8], bfr[4];

    // prologue: stage step c0
    STAGE(c0, 0)
    __syncthreads();

    for (int t = c0; t < tEnd; ++t) {
        const int  buf  = (t - c0) & 1;
        const bool more = (t + 1 < tEnd);
        if (more) STAGE(t + 1, buf ^ 1)  // in flight across this step

#pragma unroll
        for (int kg = 0; kg < 2; ++kg) {
#pragma unroll
            for (int mi = 0; mi < 8; ++mi)
                afr[mi] = *(const v8s*)(Ls + ((buf * 64)
                           + (waveM * 8 + mi) * 2 + kg) * 512 + lane * 8);
#pragma unroll
            for (int ni = 0; ni < 4; ++ni)
                bfr[ni] = *(const v8s*)(Ls + ((buf * 64) + 32
                           + (waveN * 4 + ni) * 2 + kg) * 512 + lane * 8);
#pragma unroll
            for (int mi = 0; mi < 8; ++mi)
#pragma unroll
                for (int ni = 0; ni < 4; ++ni)
                    acc[mi][ni] = __builtin_amdgcn_mfma_f32_16x16x32_bf16(
                        afr[mi], bfr[ni], acc[mi][ni], 0, 0, 0);
        }

        if (more) __syncthreads();  // gates buffer reuse; staging t+1 landed
    }
#undef STAGE

    // Epilogue: C/D mapping (verified): col = lane&15, row = quad*4 + reg.
#pragma unroll
    for (int mi = 0; mi < 8; mi++) {
#pragma unroll
        for (int r = 0; r < 4; r++) {
            const int bb = blockM + waveM * 128 + mi * 16 + quad * 4 + r;
            const float* xr = Xf + (size_t)bb * F + blockN + waveN * 64 + l16;
            float pv = acc[mi][0][r] * xr[0]
                     + acc[mi][1][r] * xr[16]
                     + acc[mi][2][r] * xr[32]
                     + acc[mi][3][r] * xr[48];
            pv += __shfl_xor(pv, 1);
            pv += __shfl_xor(pv, 2);
            pv += __shfl_xor(pv, 4);
            pv += __shfl_xor(pv, 8);
            if (l16 == 0) atomicAdd(&rowacc[bb], pv);
        }
    }
}

__global__ void sigmoid_kernel(const float* __restrict__ acc, float* __restrict__ out) {
    int b = blockIdx.x * blockDim.x + threadIdx.x;
    out[b] = 1.0f / (1.0f + __expf(-acc[b]));
}

// Correctness fallback if workspace is too small: direct per-row computation.
__global__ void fallback_kernel(const float* __restrict__ x, const float* __restrict__ w,
                                float* __restrict__ out) {
    __shared__ float xs[F];
    __shared__ float partial[4];
    const int b = blockIdx.x;
    for (int i = threadIdx.x; i < F; i += 256) xs[i] = x[(size_t)b * F + i];
    __syncthreads();
    float s = 0.0f;
    for (int i = threadIdx.x; i < F - 1; i += 256) {
        const float xi = xs[i];
        const int kbase = i * (F - 1) - (i * (i - 1)) / 2 - i - 1;
        for (int j = i + 1; j < F; j++) s += w[kbase + j] * xi * xs[j];
    }
    for (int off = 32; off; off >>= 1) s += __shfl_down(s, off);
    if ((threadIdx.x & 63) == 0) partial[threadIdx.x >> 6] = s;
    __syncthreads();
    if (threadIdx.x == 0) {
        float t = partial[0] + partial[1] + partial[2] + partial[3];
        out[b] = 1.0f / (1.0f + __expf(-t));
    }
}

extern "C" void kernel_launch(void* const* d_in, const int* in_sizes, int n_in,
                              void* d_out, int out_size, void* d_ws, size_t ws_size,
                              hipStream_t stream) {
    const float* x = (const float*)d_in[0];
    const float* w = (const float*)d_in[1];
    float* out = (float*)d_out;

    const size_t acc_bytes = 65536;                       // 16384 fp32 (rounded)
    const size_t B_bytes   = (size_t)F * F * 2;           // 2 MiB packed triangular W
    const size_t Xp_bytes  = (size_t)B_ROWS * F * 2;      // 32 MiB packed X
    const size_t needed = acc_bytes + B_bytes + Xp_bytes;

    if (ws_size < needed) {
        fallback_kernel<<<B_ROWS, 256, 0, stream>>>(x, w, out);
        return;
    }

    // Allow 128 KB dynamic LDS for the gemm (once; before graph capture use).
    static bool lds_inited = false;
    if (!lds_inited) {
        hipFuncSetAttribute((const void*)gemm_kernel,
                            hipFuncAttributeMaxDynamicSharedMemorySize, 131072);
        lds_inited = true;
    }

    float*    acc = (float*)d_ws;
    ushort_t* Bp  = (ushort_t*)((char*)d_ws + acc_bytes);
    ushort_t* Xp  = (ushort_t*)((char*)d_ws + acc_bytes + B_bytes);

    // prep: 64 (acc zero) + 512 (pack B) + 8192 (pack X)
    prep_kernel<<<64 + 512 + 8192, 256, 0, stream>>>(w, x, Bp, Xp, acc);
    // 64 M-tiles x 8 balanced triangular jobs (6+4 BK-64 steps per CU)
    gemm_kernel<<<512, 512, 131072, stream>>>(Xp, Bp, x, acc);
    sigmoid_kernel<<<B_ROWS / 256, 256, 0, stream>>>(acc, out);
}

// Round 17
// 140.181 us; speedup vs baseline: 1.0823x; 1.0823x over previous
//
#include <hip/hip_runtime.h>
#include <hip/hip_bf16.h>

#define F 1024
#define B_ROWS 16384

typedef short v8s __attribute__((ext_vector_type(8)));
typedef float v4f __attribute__((ext_vector_type(4)));
typedef unsigned short v8u __attribute__((ext_vector_type(8)));
typedef unsigned short ushort_t;

__device__ __forceinline__ unsigned short f2bf(float f) {
    unsigned int u = __builtin_bit_cast(unsigned int, f);
    u = (u + 0x7FFFu + ((u >> 16) & 1u)) >> 16;  // RNE
    return (unsigned short)u;
}

// async global->LDS, 16B per lane. LDS dest = wave-uniform base + lane*16.
__device__ __forceinline__ void gload_lds16(const ushort_t* g, ushort_t* l) {
    __builtin_amdgcn_global_load_lds(
        (const __attribute__((address_space(1))) unsigned int*)g,
        (__attribute__((address_space(3))) unsigned int*)l,
        16, 0, 0);
}

// Chunk (rb, cb) = 16-row x 32-col bf16 block stored [lane][8 bf16] in MFMA
// operand order: lane l -> row rb*16 + (l&15), cols cb*32 + (l>>4)*8..+8.
// One chunk = 1 KB. B = strictly upper-triangular W ((n,k) = w_{kn}, k<n).
// N-tile nt needs K < 128*(nt+1): 56% of the full-GEMM MACs.
//
// POISON LOG (keep forever):
//  - fused-sigmoid epilogue in gemm: CONVICTED (MfmaUtil 20->4.4%). Separate.
//  - X-pack fused as per-wave fp32 loads+cvts on MFMA path (r17): FAILED.
//  - K-split with extra blocks (r18): REGRESSION (prologue/refetch cost).
//  - fp32-A staged via gload_lds + post-LDS cvt_pk (r20/r21): FAILED
//    (cvts+extra ds_reads on critical path; 4KB/lane-stride A-gather).
//  - ring-3/counted-vmcnt/no-drain barriers on 128x128: 3x NEUTRAL.
//  - nt-remap CU balance (r25): NEUTRAL. Balance is not the constraint.
//  - 256x256/BK64/128KB-LDS (r26): FAILED 56.5us. 1 block/CU -> zero
//    inter-block TLP at the barrier; AND consecutive-block job map broke
//    M-tile<->XCD affinity -> A-panel fetched per-XCD (FETCH 54->108MB).
//    KEEP xcd = b&7 affinity (jobs of an M-tile at b, b+128, ... = same XCD).
//  - NOTE from r22 counters: VGPR 72 + 64 acc = 129-256 reg bucket -> the
//    m97 loop runs 8 waves/CU = 2 blocks/CU (not 4).
//
// r19/r22 (BEST, 128.2us): m97 structure, 128x128, BK=32, 2-buffer
// __syncthreads, both operands via gload_lds from packed chunks.
// r27 (this): BK=64 at the same 128x128 tile. We are register-capped at
// 2 blocks/CU regardless; 64KB LDS also caps at 2 -> doubling BK costs no
// occupancy, HALVES the barrier count, and doubles per-wave MFMA per drain
// (32 MFMA ~ 310cyc cover). m132's BK-scaling without m132's occupancy loss.

// prep: [0,64) zero rowacc; [64,576) pack triangular B; [576,8768) pack X.
__global__ __launch_bounds__(256) void prep_kernel(
        const float* __restrict__ w, const float* __restrict__ x,
        ushort_t* __restrict__ Bp, ushort_t* __restrict__ Xp,
        float* __restrict__ acc) {
    const int bid  = blockIdx.x;
    const int tid  = threadIdx.x;
    const int lane = tid & 63;
    const int wave = tid >> 6;
    const int l16  = lane & 15;
    const int quad = lane >> 4;

    if (bid < 64) {
        acc[bid * 256 + tid] = 0.0f;
    } else if (bid < 576) {
        const int c  = (bid - 64) * 4 + wave;    // 0..2047
        const int n  = (c >> 5) * 16 + l16;      // output-col axis
        const int k0 = (c & 31) * 32 + quad * 8; // contraction axis
        v8u o;
#pragma unroll
        for (int e = 0; e < 8; ++e) {
            const int k = k0 + e;
            float v = 0.0f;
            if (k < n) {  // strictly upper: pair (k,n), k<n
                const int idx = k * (F - 1) - (k * (k - 1)) / 2 + (n - k - 1);
                v = w[idx];  // scattered read; w = 2MB, L2-resident
            }
            o[e] = f2bf(v);
        }
        *(v8u*)(Bp + (size_t)c * 512 + lane * 8) = o;
    } else {
        const int c  = (bid - 576) * 4 + wave;  // 0..32767
        const int r  = (c >> 5) * 16 + l16;     // X row
        const int k0 = (c & 31) * 32 + quad * 8;
        const float* src = x + (size_t)r * F + k0;
        float4 v0 = *(const float4*)(src);
        float4 v1 = *(const float4*)(src + 4);
        v8u o;
        o[0] = f2bf(v0.x); o[1] = f2bf(v0.y); o[2] = f2bf(v0.z); o[3] = f2bf(v0.w);
        o[4] = f2bf(v1.x); o[5] = f2bf(v1.y); o[6] = f2bf(v1.z); o[7] = f2bf(v1.w);
        *(v8u*)(Xp + (size_t)c * 512 + lane * 8) = o;
    }
}

// m97-structure GEMM, triangular-K, BK=64 (r27). 128x128 block, 2x2 waves.
// LDS: 2 bufs x (16 A-chunks + 16 B-chunks) x 1KB = 64 KB.
// Slot layout per buf: 0-15 = A (rg*2 + kgl), 16-31 = B (ng*2 + kgl).
__global__ __launch_bounds__(256, 3) void gemm_kernel(
        const ushort_t* __restrict__ Xp,   // packed X chunks
        const ushort_t* __restrict__ Bp,   // packed triangular-W chunks
        const float*   __restrict__ Xf,    // fp32 X (epilogue)
        float*         __restrict__ rowacc) {
    __shared__ ushort_t Ls[2 * 32 * 512];  // 64 KB

    const int b   = blockIdx.x;          // 0..1023
    const int xcd = b & 7;               // M-tile<->XCD affinity (keep!)
    const int g   = b >> 3;              // 0..127
    const int y   = g & 15;
    const int nt  = 7 - (g >> 4);        // heavy (nt=7) first
    const int blockM = (xcd * 16 + y) * 128;
    const int blockN = nt * 128;
    const int tEnd   = 2 * (nt + 1);     // BK=64 steps: K < 128*(nt+1)

    const int tid   = threadIdx.x;
    const int lane  = tid & 63;
    const int wave  = tid >> 6;
    const int waveM = wave >> 1;
    const int waveN = wave & 1;
    const int quad  = lane >> 4;
    const int l16   = lane & 15;

    const int mgBase = blockM >> 4;      // first A row-group (of 8)
    const int ngB    = nt * 8;           // first B row-group (of 8)

    // Staging: 32 chunks/step (16 A + 16 B), 8 per wave, wave-uniform
    // slot = qq, per-lane 16B. A chunk qq<16: row-group qq>>1, kg qq&1.
#define STAGE(t, buf)                                                          \
    {                                                                          \
        _Pragma("unroll")                                                      \
        for (int q = 0; q < 8; ++q) {                                          \
            const int qq = wave * 8 + q;                                       \
            const ushort_t* src;                                               \
            if (qq < 16) {                                                     \
                src = Xp + ((size_t)(mgBase + (qq >> 1)) * 32                  \
                            + 2 * (t) + (qq & 1)) * 512 + lane * 8;            \
            } else {                                                           \
                src = Bp + ((size_t)(ngB + ((qq - 16) >> 1)) * 32              \
                            + 2 * (t) + (qq & 1)) * 512 + lane * 8;            \
            }                                                                  \
            gload_lds16(src, Ls + ((buf) * 32 + qq) * 512);                    \
        }                                                                      \
    }

    v4f acc[4][4];
#pragma unroll
    for (int i = 0; i < 4; i++)
#pragma unroll
        for (int j = 0; j < 4; j++) acc[i][j] = (v4f)(0.0f);

    v8s afr[4], bfr[4];

    // prologue: stage BK-64 step 0
    STAGE(0, 0)
    __syncthreads();

    for (int t = 0; t < tEnd; ++t) {
        const int  buf  = t & 1;
        const bool more = (t + 1 < tEnd);
        if (more) STAGE(t + 1, buf ^ 1)  // in flight across this step

#pragma unroll
        for (int kg = 0; kg < 2; ++kg) {
#pragma unroll
            for (int mi = 0; mi < 4; ++mi)
                afr[mi] = *(const v8s*)(Ls + (buf * 32
                           + (waveM * 4 + mi) * 2 + kg) * 512 + lane * 8);
#pragma unroll
            for (int ni = 0; ni < 4; ++ni)
                bfr[ni] = *(const v8s*)(Ls + (buf * 32 + 16
                           + (waveN * 4 + ni) * 2 + kg) * 512 + lane * 8);
#pragma unroll
            for (int mi = 0; mi < 4; ++mi)
#pragma unroll
                for (int ni = 0; ni < 4; ++ni)
                    acc[mi][ni] = __builtin_amdgcn_mfma_f32_16x16x32_bf16(
                        afr[mi], bfr[ni], acc[mi][ni], 0, 0, 0);
        }

        if (more) __syncthreads();  // gates buffer reuse; staging t+1 landed
    }
#undef STAGE

    // Epilogue: C/D mapping (verified): col = lane&15, row = quad*4 + reg.
#pragma unroll
    for (int mi = 0; mi < 4; mi++) {
#pragma unroll
        for (int r = 0; r < 4; r++) {
            const int bb = blockM + waveM * 64 + mi * 16 + quad * 4 + r;
            const float* xr = Xf + (size_t)bb * F + blockN + waveN * 64 + l16;
            float pv = acc[mi][0][r] * xr[0]
                     + acc[mi][1][r] * xr[16]
                     + acc[mi][2][r] * xr[32]
                     + acc[mi][3][r] * xr[48];
            pv += __shfl_xor(pv, 1);
            pv += __shfl_xor(pv, 2);
            pv += __shfl_xor(pv, 4);
            pv += __shfl_xor(pv, 8);
            if (l16 == 0) atomicAdd(&rowacc[bb], pv);
        }
    }
}

__global__ void sigmoid_kernel(const float* __restrict__ acc, float* __restrict__ out) {
    int b = blockIdx.x * blockDim.x + threadIdx.x;
    out[b] = 1.0f / (1.0f + __expf(-acc[b]));
}

// Correctness fallback if workspace is too small: direct per-row computation.
__global__ void fallback_kernel(const float* __restrict__ x, const float* __restrict__ w,
                                float* __restrict__ out) {
    __shared__ float xs[F];
    __shared__ float partial[4];
    const int b = blockIdx.x;
    for (int i = threadIdx.x; i < F; i += 256) xs[i] = x[(size_t)b * F + i];
    __syncthreads();
    float s = 0.0f;
    for (int i = threadIdx.x; i < F - 1; i += 256) {
        const float xi = xs[i];
        const int kbase = i * (F - 1) - (i * (i - 1)) / 2 - i - 1;
        for (int j = i + 1; j < F; j++) s += w[kbase + j] * xi * xs[j];
    }
    for (int off = 32; off; off >>= 1) s += __shfl_down(s, off);
    if ((threadIdx.x & 63) == 0) partial[threadIdx.x >> 6] = s;
    __syncthreads();
    if (threadIdx.x == 0) {
        float t = partial[0] + partial[1] + partial[2] + partial[3];
        out[b] = 1.0f / (1.0f + __expf(-t));
    }
}

extern "C" void kernel_launch(void* const* d_in, const int* in_sizes, int n_in,
                              void* d_out, int out_size, void* d_ws, size_t ws_size,
                              hipStream_t stream) {
    const float* x = (const float*)d_in[0];
    const float* w = (const float*)d_in[1];
    float* out = (float*)d_out;

    const size_t acc_bytes = 65536;                       // 16384 fp32 (rounded)
    const size_t B_bytes   = (size_t)F * F * 2;           // 2 MiB packed triangular W
    const size_t Xp_bytes  = (size_t)B_ROWS * F * 2;      // 32 MiB packed X
    const size_t needed = acc_bytes + B_bytes + Xp_bytes;

    if (ws_size < needed) {
        fallback_kernel<<<B_ROWS, 256, 0, stream>>>(x, w, out);
        return;
    }

    float*    acc = (float*)d_ws;
    ushort_t* Bp  = (ushort_t*)((char*)d_ws + acc_bytes);
    ushort_t* Xp  = (ushort_t*)((char*)d_ws + acc_bytes + B_bytes);

    // prep: 64 (acc zero) + 512 (pack B) + 8192 (pack X)
    prep_kernel<<<64 + 512 + 8192, 256, 0, stream>>>(w, x, Bp, Xp, acc);
    // 128 M-tiles x 8 N-tiles; per-block K-extent 2*(nt+1) BK-64 steps
    gemm_kernel<<<1024, 256, 0, stream>>>(Xp, Bp, x, acc);
    sigmoid_kernel<<<B_ROWS / 256, 256, 0, stream>>>(acc, out);
}